// Round 6
// baseline (175.102 us; speedup 1.0000x reference)
//
#include <hip/hip_runtime.h>
#include <math.h>

#define NB 8
#define KC 64
#define S1C 5
#define CC 128
#define PP 1936
#define MM 320             /* KC*S1C */
#define PT 16
#define NPT 121            /* 1936/16 exactly -> no tail */
#define NTILE (NB * NPT)   /* 968 */
#define ALPHAF 1500.0f
#define EPSF 1e-12f

/* main-path ws (floats): part[968][64][128] ; ps[968][64]  = ~32 MB */
#define WS_PS   ((size_t)NTILE * KC * CC)
#define WS_MAIN_FLOATS (WS_PS + (size_t)NTILE * KC)
/* fallback ws: accC[8][64][128] ; accS[8][64] (atomics + memset) */
#define WS_FB_ZERO_BYTES ((size_t)(NB * KC * CC + NB * KC) * 4)

// ---------------------------------------------------------------------------
// k1: per (n, p-tile of 16), 256 threads = 4 waves, 4 blocks/CU co-resident.
// Same per-wave work as R4; barriers now overlap across 4 independent blocks.
// thread -> (p = tid&15, kg = tid>>4); k = kg + 16*j, j<4; beta in registers.
// ---------------------------------------------------------------------------
__global__ __launch_bounds__(256, 4) void k1_main(
    const float* __restrict__ x, const float* __restrict__ cen,
    float* __restrict__ sa_out, float* __restrict__ outC,
    float* __restrict__ outS, int mode)
{
    __shared__ float  xs[PT][132];     // 8.4 KB  x tile, p-major (+4 pad)
    __shared__ float  war[PT * 68];    // 4.4 KB  wa, k-remapped: [p][(k&7)*8+(k>>3)]
    __shared__ float2 ap[16 * 17];     // 2.2 KB  alpha partials [kg][p] (+1 row pad)
    __shared__ float  bias[MM];        // 1.3 KB

    const int tid = threadIdx.x;
    const int p   = tid & 15;
    const int kg  = tid >> 4;          // 0..15
    const int bx  = blockIdx.x;
    const int n   = bx / NPT;
    const int pt  = bx - n * NPT;
    const int p0  = pt * PT;

    // ---- stage x tile: xs[pp][c] = x[n][c][p0+pp] ----
    const float* xn = x + (size_t)n * CC * PP;
    for (int r = 0; r < 2; ++r) {
        const int idx = tid + 256 * r;          // 512 float4 total
        const int c = idx >> 2;
        const int q = idx & 3;
        const float4 v = *(const float4*)(xn + (size_t)c * PP + p0 + 4 * q);
        xs[4 * q + 0][c] = v.x;
        xs[4 * q + 1][c] = v.y;
        xs[4 * q + 2][c] = v.z;
        xs[4 * q + 3][c] = v.w;
    }
    // ---- bias[m] = -ALPHA*||cen_m|| (rows tid and 256+tid) ----
    {
        const float4* row = (const float4*)(cen + (size_t)tid * CC);
        float ss = 0.f;
#pragma unroll
        for (int c4 = 0; c4 < 32; ++c4) {
            const float4 v = row[c4];
            ss += v.x * v.x + v.y * v.y + v.z * v.z + v.w * v.w;
        }
        bias[tid] = -ALPHAF * sqrtf(ss);
        if (tid < MM - 256) {
            const float4* row2 = (const float4*)(cen + (size_t)(256 + tid) * CC);
            float s2 = 0.f;
#pragma unroll
            for (int c4 = 0; c4 < 32; ++c4) {
                const float4 v = row2[c4];
                s2 += v.x * v.x + v.y * v.y + v.z * v.z + v.w * v.w;
            }
            bias[256 + tid] = -ALPHAF * sqrtf(s2);
        }
    }
    __syncthreads();

    // ---- logits: acc[j][s] for k = kg+16j ----
    const float4* wb = (const float4*)cen;
    int rb[4];
#pragma unroll
    for (int j = 0; j < 4; ++j) rb[j] = (kg + 16 * j) * 160;   // m*32, m=k*5

    float acc[4][5];
#pragma unroll
    for (int j = 0; j < 4; ++j)
#pragma unroll
        for (int s = 0; s < 5; ++s) acc[j][s] = 0.f;

#pragma unroll 2
    for (int c4 = 0; c4 < 32; ++c4) {
        const float4 xv = *(const float4*)(&xs[p][4 * c4]);
#pragma unroll
        for (int j = 0; j < 4; ++j) {
#pragma unroll
            for (int s = 0; s < 5; ++s) {
                const float4 w = wb[rb[j] + s * 32 + c4];
                acc[j][s] += w.x * xv.x + w.y * xv.y + w.z * xv.z + w.w * xv.w;
            }
        }
    }

    // ---- beta softmax (registers) + per-thread alpha partial ----
    float lg0_r[4], beta_r[4];
#pragma unroll
    for (int j = 0; j < 4; ++j) {
        const int k = kg + 16 * j;
        float lg[5];
#pragma unroll
        for (int s = 0; s < 5; ++s)
            lg[s] = 2.f * ALPHAF * acc[j][s] + bias[k * S1C + s];
        const float m5 = fmaxf(fmaxf(fmaxf(lg[0], lg[1]), fmaxf(lg[2], lg[3])), lg[4]);
        const float e0 = __expf(lg[0] - m5);
        const float den = e0 + __expf(lg[1] - m5) + __expf(lg[2] - m5) +
                          __expf(lg[3] - m5) + __expf(lg[4] - m5);
        beta_r[j] = e0 / den;
        lg0_r[j]  = lg[0];
    }
    {
        const float mx = fmaxf(fmaxf(lg0_r[0], lg0_r[1]), fmaxf(lg0_r[2], lg0_r[3]));
        const float se = __expf(lg0_r[0] - mx) + __expf(lg0_r[1] - mx) +
                         __expf(lg0_r[2] - mx) + __expf(lg0_r[3] - mx);
        ap[kg * 17 + p] = make_float2(mx, se);
    }
    __syncthreads();

    // ---- alpha finalize (each thread, for its own p) ----
    float gm = -3.0e38f;
#pragma unroll
    for (int w = 0; w < 16; ++w) gm = fmaxf(gm, ap[w * 17 + p].x);
    float sum = 0.f;
#pragma unroll
    for (int w = 0; w < 16; ++w) {
        const float2 v = ap[w * 17 + p];
        sum += v.y * __expf(v.x - gm);
    }
    const float arcs = 1.0f / sum;

    // ---- sa out + war (k-remapped) + ps via 16-lane shfl ----
    float* san = sa_out + (size_t)n * KC * PP;
#pragma unroll
    for (int j = 0; j < 4; ++j) {
        const int k = kg + 16 * j;
        const float sa = __expf(lg0_r[j] - gm) * arcs * beta_r[j];
        san[(size_t)k * PP + p0 + p] = sa;
        const float wa = 1.0f + sa;
        war[p * 68 + (kg & 7) * 8 + (kg >> 3) + 2 * j] = wa;
        float ssum = wa;                 // reduce over p (lanes l^1,2,4,8 stay in 16-group)
        ssum += __shfl_xor(ssum, 1);
        ssum += __shfl_xor(ssum, 2);
        ssum += __shfl_xor(ssum, 4);
        ssum += __shfl_xor(ssum, 8);
        if (p == 0) {
            if (mode == 0) outS[(size_t)bx * KC + k] = ssum;
            else           atomicAdd(&outS[(size_t)n * KC + k], ssum);
        }
    }
    __syncthreads();

    // ---- stage-C: C[k][c] = sum_p wa*x ; thread = (cq = tid&31 -> 4c, kq = tid>>5 -> 8k) ----
    const int cq = tid & 31;
    const int kq = tid >> 5;             // 0..7 ; k = kq + 8*t
    float a0[8], a1[8], a2[8], a3[8];
#pragma unroll
    for (int t = 0; t < 8; ++t) { a0[t] = a1[t] = a2[t] = a3[t] = 0.f; }

#pragma unroll 4
    for (int pp = 0; pp < PT; ++pp) {
        const float4 xv  = *(const float4*)(&xs[pp][4 * cq]);
        const float4 wv0 = *(const float4*)(&war[pp * 68 + kq * 8]);
        const float4 wv1 = *(const float4*)(&war[pp * 68 + kq * 8 + 4]);
        const float w[8] = {wv0.x, wv0.y, wv0.z, wv0.w, wv1.x, wv1.y, wv1.z, wv1.w};
#pragma unroll
        for (int t = 0; t < 8; ++t) {    // war idx kq*8+t -> k = kq + 8*t
            a0[t] += w[t] * xv.x;
            a1[t] += w[t] * xv.y;
            a2[t] += w[t] * xv.z;
            a3[t] += w[t] * xv.w;
        }
    }
    if (mode == 0) {
        float* dst = outC + (size_t)bx * KC * CC;
#pragma unroll
        for (int t = 0; t < 8; ++t) {
            float4 o = make_float4(a0[t], a1[t], a2[t], a3[t]);
            *(float4*)(&dst[(kq + 8 * t) * CC + 4 * cq]) = o;
        }
    } else {
        float* dst = outC + (size_t)n * KC * CC;
#pragma unroll
        for (int t = 0; t < 8; ++t) {
            const int base = (kq + 8 * t) * CC + 4 * cq;
            atomicAdd(&dst[base + 0], a0[t]);
            atomicAdd(&dst[base + 1], a1[t]);
            atomicAdd(&dst[base + 2], a2[t]);
            atomicAdd(&dst[base + 3], a3[t]);
        }
    }
}

// ---------------------------------------------------------------------------
// k2 (slab mode): reduce 121 partial slabs, subtract rep*Swa, normalize, /8
// ---------------------------------------------------------------------------
__global__ __launch_bounds__(128) void k2_slab(
    const float* __restrict__ part, const float* __restrict__ ps,
    const float* __restrict__ cen, float* __restrict__ flat)
{
    __shared__ float redA[2];
    __shared__ float redB[2];
    const int b = blockIdx.x;        // n*64 + k
    const int n = b >> 6;
    const int k = b & 63;
    const int c = threadIdx.x;       // 0..127

    // Swa = sum over 121 tiles of ps
    float pv = 0.f;
    if (c < NPT) pv = ps[((size_t)n * NPT + c) * KC + k];
#pragma unroll
    for (int off = 32; off > 0; off >>= 1) pv += __shfl_down(pv, off);
    if ((c & 63) == 0) redA[c >> 6] = pv;
    __syncthreads();
    const float sw = redA[0] + redA[1];

    const float* pb = part + (size_t)n * NPT * KC * CC + (size_t)k * CC + c;
    float v = 0.f;
#pragma unroll 8
    for (int pt = 0; pt < NPT; ++pt) v += pb[(size_t)pt * KC * CC];
    v -= cen[(size_t)k * S1C * CC + c] * sw;

    float ss = v * v;
#pragma unroll
    for (int off = 32; off > 0; off >>= 1) ss += __shfl_down(ss, off);
    if ((c & 63) == 0) redB[c >> 6] = ss;
    __syncthreads();
    const float norm = sqrtf(redB[0] + redB[1]);
    // flat-level norm is exactly sqrt(64)=8 (every row unit-norm, >> EPS)
    const float scale = 1.0f / (fmaxf(norm, EPSF) * 8.0f);
    flat[(size_t)b * CC + c] = v * scale;
}

// ---------------------------------------------------------------------------
// k2 (fallback/atomic mode)
// ---------------------------------------------------------------------------
__global__ __launch_bounds__(128) void k2_final(
    const float* __restrict__ accC, const float* __restrict__ accS,
    const float* __restrict__ cen, float* __restrict__ flat)
{
    __shared__ float w2[2];
    const int b = blockIdx.x;
    const int k = b & 63;
    const int c = threadIdx.x;
    const float v = accC[(size_t)b * CC + c] -
                    cen[(size_t)k * S1C * CC + c] * accS[b];
    float ss = v * v;
#pragma unroll
    for (int off = 32; off > 0; off >>= 1) ss += __shfl_down(ss, off);
    if ((c & 63) == 0) w2[c >> 6] = ss;
    __syncthreads();
    const float norm = sqrtf(w2[0] + w2[1]);
    const float scale = 1.0f / (fmaxf(norm, EPSF) * 8.0f);
    flat[(size_t)b * CC + c] = v * scale;
}

// ---------------------------------------------------------------------------
extern "C" void kernel_launch(void* const* d_in, const int* in_sizes, int n_in,
                              void* d_out, int out_size, void* d_ws, size_t ws_size,
                              hipStream_t stream) {
    const float* x   = (const float*)d_in[0];   // [8][128][44][44]
    const float* cen = (const float*)d_in[1];   // [64][5][128]
    float* out  = (float*)d_out;
    float* flat = out;                           // [8][8192]
    float* sa   = out + (size_t)NB * KC * CC;    // [8][64][1][1936]
    float* ws   = (float*)d_ws;

    if (ws_size >= WS_MAIN_FLOATS * 4) {
        // main path: per-tile slabs, no atomics, no memset
        float* part = ws;
        float* ps   = ws + WS_PS;
        k1_main<<<NTILE, 256, 0, stream>>>(x, cen, sa, part, ps, 0);
        k2_slab<<<NB * KC, 128, 0, stream>>>(part, ps, cen, flat);
    } else {
        // fallback: atomics into per-n accumulators (memset first)
        float* accC = ws;
        float* accS = ws + NB * KC * CC;
        hipMemsetAsync(d_ws, 0, WS_FB_ZERO_BYTES, stream);
        k1_main<<<NTILE, 256, 0, stream>>>(x, cen, sa, accC, accS, 1);
        k2_final<<<NB * KC, 128, 0, stream>>>(accC, accS, cen, flat);
    }
}

// Round 7
// 94.291 us; speedup vs baseline: 1.8570x; 1.8570x over previous
//
#include <hip/hip_runtime.h>
#include <math.h>

#define NB 8
#define KC 64
#define S1C 5
#define CC 128
#define PP 1936
#define MM 320             /* KC*S1C */
#define PT 64
#define NPT 31             /* ceil(1936/64) */
#define NTILE (NB * NPT)   /* 248 */
#define ALPHAF 1500.0f
#define EPSF 1e-12f

/* main-path ws (floats): part[248][64][128] ; ps[248][64] = 8.19 MB */
#define WS_PS   ((size_t)NTILE * KC * CC)
#define WS_MAIN_FLOATS (WS_PS + (size_t)NTILE * KC)
#define WS_FB_ZERO_BYTES ((size_t)(NB * KC * CC + NB * KC) * 4)

typedef __attribute__((ext_vector_type(8))) short short8;
typedef __attribute__((ext_vector_type(4))) float f32x4;

/* pack fp32 -> (bf16_hi << 16) | bf16_lo  (hi = truncate, lo = residual) */
__device__ __forceinline__ unsigned pack_bf16s(float x) {
    unsigned u  = __float_as_uint(x);
    unsigned hi = u & 0xffff0000u;
    float lo    = x - __uint_as_float(hi);
    return hi | (__float_as_uint(lo) >> 16);
}

__device__ __forceinline__ void unpack8(const int4 q0, const int4 q1,
                                        short8& h, short8& l) {
    const int d[8] = {q0.x, q0.y, q0.z, q0.w, q1.x, q1.y, q1.z, q1.w};
#pragma unroll
    for (int j = 0; j < 8; ++j) {
        h[j] = (short)((unsigned)d[j] >> 16);
        l[j] = (short)((unsigned)d[j] & 0xffffu);
    }
}

__device__ __forceinline__ void split8(const float4 a, const float4 b,
                                       short8& h, short8& l) {
    const float f[8] = {a.x, a.y, a.z, a.w, b.x, b.y, b.z, b.w};
#pragma unroll
    for (int j = 0; j < 8; ++j) {
        const unsigned u  = __float_as_uint(f[j]);
        const unsigned hi = u & 0xffff0000u;
        const float lo    = f[j] - __uint_as_float(hi);
        h[j] = (short)(hi >> 16);
        l[j] = (short)(__float_as_uint(lo) >> 16);
    }
}

// ---------------------------------------------------------------------------
// k1: per (n, p-tile of 64), 1024 threads = 16 waves, 3 barriers.
// Logits via MFMA: D[p][m'] = x^T cen, m' = 8k+s padded (s>=5 masked).
// Wave handles m'-tiles nt = {2wid, 2wid+1} -> k = 4wid..4wid+3.
// beta: 8-lane shfl butterflies. alpha: per-wave partials + per-lane finalize.
// stage-C via bf16-split MFMA (R5-validated).
// ---------------------------------------------------------------------------
__global__ __launch_bounds__(1024, 4) void k1_main(
    const float* __restrict__ x, const float* __restrict__ cen,
    float* __restrict__ sa_out, float* __restrict__ outC,
    float* __restrict__ outS, int mode)
{
    __shared__ unsigned xbuf[CC * 68];   // 34816 B; phase1: [p][132] packed x^T; phase3: [c][68] packed x
    __shared__ unsigned war[KC * 68];    // 17408 B packed wa [k][p]
    __shared__ float2   ap[16 * 66];     //  8448 B alpha partials [wid][p]
    __shared__ float    bias_p[512];     //  2048 B padded bias, m' = 8k+s

    const int tid  = threadIdx.x;
    const int lane = tid & 63;
    const int wid  = tid >> 6;           // 0..15
    const int quad = lane >> 4;
    const int l15  = lane & 15;
    const int bx   = blockIdx.x;
    const int n    = bx / NPT;
    const int pt   = bx - n * NPT;
    const int p0   = pt * PT;

    // ---- phase 0: stage x -> xbuf[p][132] packed bf16 hi|lo; bias ----
    const float* xn = x + (size_t)n * CC * PP;
    for (int idx = tid; idx < CC * 16; idx += 1024) {
        const int c = idx >> 4;
        const int q = idx & 15;
        const int p = 4 * q;
        float4 v = make_float4(0.f, 0.f, 0.f, 0.f);
        if (p0 + p < PP) v = *(const float4*)(xn + (size_t)c * PP + p0 + p);
        xbuf[(p + 0) * 132 + c] = pack_bf16s(v.x);
        xbuf[(p + 1) * 132 + c] = pack_bf16s(v.y);
        xbuf[(p + 2) * 132 + c] = pack_bf16s(v.z);
        xbuf[(p + 3) * 132 + c] = pack_bf16s(v.w);
    }
    if (tid < 192) bias_p[8 * (tid / 3) + 5 + (tid % 3)] = -3.0e38f;
    if (tid < MM) {
        const float4* row = (const float4*)(cen + (size_t)tid * CC);
        float ss = 0.f;
#pragma unroll
        for (int c4 = 0; c4 < 32; ++c4) {
            const float4 v = row[c4];
            ss += v.x * v.x + v.y * v.y + v.z * v.z + v.w * v.w;
        }
        bias_p[8 * (tid / 5) + (tid % 5)] = -ALPHAF * sqrtf(ss);
    }
    __syncthreads();

    // ---- phase 1: logits MFMA ----
    f32x4 dacc[4][2];
#pragma unroll
    for (int a = 0; a < 4; ++a) {
        dacc[a][0] = (f32x4){0.f, 0.f, 0.f, 0.f};
        dacc[a][1] = (f32x4){0.f, 0.f, 0.f, 0.f};
    }
    int mp[2], wrow[2]; bool wvalid[2];
#pragma unroll
    for (int i = 0; i < 2; ++i) {
        mp[i] = (2 * wid + i) * 16 + l15;          // m' column
        const int s = mp[i] & 7;
        wvalid[i] = (s < 5);
        wrow[i] = 5 * (mp[i] >> 3) + s;            // row in cen (garbage if invalid)
    }

#pragma unroll 1
    for (int ks = 0; ks < 4; ++ks) {
        short8 bh[2], bl[2];
#pragma unroll
        for (int i = 0; i < 2; ++i) {
            float4 wlo = make_float4(0.f, 0.f, 0.f, 0.f);
            float4 whi = make_float4(0.f, 0.f, 0.f, 0.f);
            if (wvalid[i]) {
                const float* wp = cen + (size_t)wrow[i] * CC + ks * 32 + quad * 8;
                wlo = *(const float4*)wp;
                whi = *(const float4*)(wp + 4);
            }
            split8(wlo, whi, bh[i], bl[i]);
        }
#pragma unroll
        for (int a = 0; a < 4; ++a) {
            const int abase = (a * 16 + l15) * 132 + ks * 32 + quad * 8;
            const int4 q0 = *(const int4*)(&xbuf[abase]);
            const int4 q1 = *(const int4*)(&xbuf[abase + 4]);
            short8 ah, al;
            unpack8(q0, q1, ah, al);
#pragma unroll
            for (int i = 0; i < 2; ++i) {
                dacc[a][i] = __builtin_amdgcn_mfma_f32_16x16x32_bf16(ah, bh[i], dacc[a][i], 0, 0, 0);
                dacc[a][i] = __builtin_amdgcn_mfma_f32_16x16x32_bf16(ah, bl[i], dacc[a][i], 0, 0, 0);
                dacc[a][i] = __builtin_amdgcn_mfma_f32_16x16x32_bf16(al, bh[i], dacc[a][i], 0, 0, 0);
            }
        }
    }

    // lg in place: lg = 2*ALPHA*dot + bias (invalid cols -> -3e38)
    const float bv0 = bias_p[mp[0]];
    const float bv1 = bias_p[mp[1]];
#pragma unroll
    for (int a = 0; a < 4; ++a)
#pragma unroll
        for (int r = 0; r < 4; ++r) {
            dacc[a][0][r] = 2.f * ALPHAF * dacc[a][0][r] + bv0;
            dacc[a][1][r] = 2.f * ALPHAF * dacc[a][1][r] + bv1;
        }

    // alpha partials over this wave's 4 k (i-regs x shfl_xor 8), s0 lanes hold lg0
#pragma unroll
    for (int a = 0; a < 4; ++a) {
        f32x4 mx4, se4;
#pragma unroll
        for (int r = 0; r < 4; ++r) {
            float m_ = fmaxf(dacc[a][0][r], dacc[a][1][r]);
            m_ = fmaxf(m_, __shfl_xor(m_, 8));
            float se = __expf(dacc[a][0][r] - m_) + __expf(dacc[a][1][r] - m_);
            se += __shfl_xor(se, 8);
            mx4[r] = m_; se4[r] = se;
        }
        if (l15 == 0) {
#pragma unroll
            for (int r = 0; r < 4; ++r)
                ap[wid * 66 + a * 16 + 4 * quad + r] = make_float2(mx4[r], se4[r]);
        }
    }
    __syncthreads();

    // ---- phase 2: alpha finalize (lane = p), beta+sa, war, xc restage ----
    float gmv, arv;
    {
        float gm = -3.0e38f;
#pragma unroll
        for (int w = 0; w < 16; ++w) gm = fmaxf(gm, ap[w * 66 + lane].x);
        float s = 0.f;
#pragma unroll
        for (int w = 0; w < 16; ++w) {
            const float2 v = ap[w * 66 + lane];
            s += v.y * __expf(v.x - gm);
        }
        gmv = gm; arv = 1.0f / s;
    }

    float* san = sa_out + (size_t)n * KC * PP;
    float psum[2] = {0.f, 0.f};
    const bool is_s0 = ((l15 & 7) == 0);
#pragma unroll
    for (int a = 0; a < 4; ++a) {
#pragma unroll
        for (int i = 0; i < 2; ++i) {
            const f32x4 lg = dacc[a][i];
            f32x4 sav; unsigned wpk[4];
#pragma unroll
            for (int r = 0; r < 4; ++r) {
                float m_ = lg[r];
                m_ = fmaxf(m_, __shfl_xor(m_, 1));
                m_ = fmaxf(m_, __shfl_xor(m_, 2));
                m_ = fmaxf(m_, __shfl_xor(m_, 4));
                const float e_ = __expf(lg[r] - m_);
                float d_ = e_;
                d_ += __shfl_xor(d_, 1);
                d_ += __shfl_xor(d_, 2);
                d_ += __shfl_xor(d_, 4);
                const int p = a * 16 + 4 * quad + r;
                const float gm_p = __shfl(gmv, p);
                const float ar_p = __shfl(arv, p);
                const float sa = __expf(lg[r] - gm_p) * ar_p * (e_ / d_);
                const bool pvalid = (p0 + p) < PP;
                const float wa = pvalid ? (1.0f + sa) : 0.0f;
                sav[r] = sa;
                wpk[r] = pack_bf16s(wa);
                psum[i] += wa;
            }
            const int k = 4 * wid + 2 * i + (l15 >> 3);
            if (is_s0) {
                *(int4*)(&war[k * 68 + a * 16 + 4 * quad]) = *(const int4*)wpk;
                const int pg = p0 + a * 16 + 4 * quad;
                if (pg < PP) *(float4*)(&san[(size_t)k * PP + pg]) = *(const float4*)&sav;
            }
        }
    }
#pragma unroll
    for (int i = 0; i < 2; ++i) {
        float s = psum[i];
        s += __shfl_xor(s, 16);
        s += __shfl_xor(s, 32);
        if (is_s0 && quad == 0) {
            const int k = 4 * wid + 2 * i + (l15 >> 3);
            if (mode == 0) outS[(size_t)bx * KC + k] = s;
            else           atomicAdd(&outS[(size_t)n * KC + k], s);
        }
    }
    // restage x -> xbuf[c][68] packed (phase-1 reads finished before barrier)
    {
        const int c  = tid >> 3;
        const int po = (tid & 7) * 8;
        float4 v0 = make_float4(0.f, 0.f, 0.f, 0.f), v1 = v0;
        if (p0 + po < PP) {
            const float* src = xn + (size_t)c * PP + p0 + po;
            v0 = *(const float4*)src;
            v1 = *(const float4*)(src + 4);
        }
        unsigned pk[8];
        pk[0] = pack_bf16s(v0.x); pk[1] = pack_bf16s(v0.y);
        pk[2] = pack_bf16s(v0.z); pk[3] = pack_bf16s(v0.w);
        pk[4] = pack_bf16s(v1.x); pk[5] = pack_bf16s(v1.y);
        pk[6] = pack_bf16s(v1.z); pk[7] = pack_bf16s(v1.w);
        *(int4*)(&xbuf[c * 68 + po])     = *(const int4*)&pk[0];
        *(int4*)(&xbuf[c * 68 + po + 4]) = *(const int4*)&pk[4];
    }
    __syncthreads();

    // ---- phase 3: stage-C MFMA: C[k][c] = sum_p wa*x ----
    const int kt  = wid & 3;
    const int ct0 = (wid >> 2) * 2;
    f32x4 cacc[2];
    cacc[0] = (f32x4){0.f, 0.f, 0.f, 0.f};
    cacc[1] = (f32x4){0.f, 0.f, 0.f, 0.f};
#pragma unroll
    for (int ks = 0; ks < 64; ks += 32) {
        const int abase = (kt * 16 + l15) * 68 + ks + quad * 8;
        const int4 qa0 = *(const int4*)(&war[abase]);
        const int4 qa1 = *(const int4*)(&war[abase + 4]);
        short8 ah, al;
        unpack8(qa0, qa1, ah, al);
#pragma unroll
        for (int t = 0; t < 2; ++t) {
            const int c = (ct0 + t) * 16 + l15;
            const int bbase = c * 68 + ks + quad * 8;
            const int4 qb0 = *(const int4*)(&xbuf[bbase]);
            const int4 qb1 = *(const int4*)(&xbuf[bbase + 4]);
            short8 bh, bl;
            unpack8(qb0, qb1, bh, bl);
            cacc[t] = __builtin_amdgcn_mfma_f32_16x16x32_bf16(ah, bh, cacc[t], 0, 0, 0);
            cacc[t] = __builtin_amdgcn_mfma_f32_16x16x32_bf16(ah, bl, cacc[t], 0, 0, 0);
            cacc[t] = __builtin_amdgcn_mfma_f32_16x16x32_bf16(al, bh, cacc[t], 0, 0, 0);
        }
    }
    if (mode == 0) {
        float* dst = outC + (size_t)bx * KC * CC;
#pragma unroll
        for (int t = 0; t < 2; ++t) {
            const int c = (ct0 + t) * 16 + l15;
#pragma unroll
            for (int r = 0; r < 4; ++r)
                dst[(kt * 16 + 4 * quad + r) * CC + c] = cacc[t][r];
        }
    } else {
        float* dst = outC + (size_t)n * KC * CC;
#pragma unroll
        for (int t = 0; t < 2; ++t) {
            const int c = (ct0 + t) * 16 + l15;
#pragma unroll
            for (int r = 0; r < 4; ++r)
                atomicAdd(&dst[(kt * 16 + 4 * quad + r) * CC + c], cacc[t][r]);
        }
    }
}

// ---------------------------------------------------------------------------
// k2 (slab mode): reduce 31 partial slabs, subtract rep*Swa, normalize, /8
// ---------------------------------------------------------------------------
__global__ __launch_bounds__(128) void k2_slab(
    const float* __restrict__ part, const float* __restrict__ ps,
    const float* __restrict__ cen, float* __restrict__ flat)
{
    __shared__ float w2[2];
    const int b = blockIdx.x;        // n*64 + k
    const int n = b >> 6;
    const int k = b & 63;
    const int c = threadIdx.x;       // 0..127
    const float* pb = part + (size_t)n * NPT * KC * CC + (size_t)k * CC + c;
    float v = 0.f;
#pragma unroll 8
    for (int pt = 0; pt < NPT; ++pt) v += pb[(size_t)pt * KC * CC];
    const float* psb = ps + (size_t)n * NPT * KC + k;
    float sw = 0.f;
#pragma unroll
    for (int pt = 0; pt < NPT; ++pt) sw += psb[(size_t)pt * KC];
    v -= cen[(size_t)k * S1C * CC + c] * sw;

    float ss = v * v;
#pragma unroll
    for (int off = 32; off > 0; off >>= 1) ss += __shfl_down(ss, off);
    if ((c & 63) == 0) w2[c >> 6] = ss;
    __syncthreads();
    const float norm = sqrtf(w2[0] + w2[1]);
    // flat-level norm is exactly sqrt(64)=8 (every row unit-norm, >> EPS)
    const float scale = 1.0f / (fmaxf(norm, EPSF) * 8.0f);
    flat[(size_t)b * CC + c] = v * scale;
}

// ---------------------------------------------------------------------------
// k2 (fallback/atomic mode)
// ---------------------------------------------------------------------------
__global__ __launch_bounds__(128) void k2_final(
    const float* __restrict__ accC, const float* __restrict__ accS,
    const float* __restrict__ cen, float* __restrict__ flat)
{
    __shared__ float w2[2];
    const int b = blockIdx.x;
    const int k = b & 63;
    const int c = threadIdx.x;
    const float v = accC[(size_t)b * CC + c] -
                    cen[(size_t)k * S1C * CC + c] * accS[b];
    float ss = v * v;
#pragma unroll
    for (int off = 32; off > 0; off >>= 1) ss += __shfl_down(ss, off);
    if ((c & 63) == 0) w2[c >> 6] = ss;
    __syncthreads();
    const float norm = sqrtf(w2[0] + w2[1]);
    const float scale = 1.0f / (fmaxf(norm, EPSF) * 8.0f);
    flat[(size_t)b * CC + c] = v * scale;
}

// ---------------------------------------------------------------------------
extern "C" void kernel_launch(void* const* d_in, const int* in_sizes, int n_in,
                              void* d_out, int out_size, void* d_ws, size_t ws_size,
                              hipStream_t stream) {
    const float* x   = (const float*)d_in[0];   // [8][128][44][44]
    const float* cen = (const float*)d_in[1];   // [64][5][128]
    float* out  = (float*)d_out;
    float* flat = out;                           // [8][8192]
    float* sa   = out + (size_t)NB * KC * CC;    // [8][64][1][1936]
    float* ws   = (float*)d_ws;

    if (ws_size >= WS_MAIN_FLOATS * 4) {
        float* part = ws;
        float* ps   = ws + WS_PS;
        k1_main<<<NTILE, 1024, 0, stream>>>(x, cen, sa, part, ps, 0);
        k2_slab<<<NB * KC, 128, 0, stream>>>(part, ps, cen, flat);
    } else {
        float* accC = ws;
        float* accS = ws + NB * KC * CC;
        hipMemsetAsync(d_ws, 0, WS_FB_ZERO_BYTES, stream);
        k1_main<<<NTILE, 1024, 0, stream>>>(x, cen, sa, accC, accS, 1);
        k2_final<<<NB * KC, 128, 0, stream>>>(accC, accS, cen, flat);
    }
}